// Round 6
// baseline (53.131 us; speedup 1.0000x reference)
//
#include <hip/hip_runtime.h>

// Chamfer loss: global (data vs rec) + per-part (data seg vs recp seg).
// 1024 uniform blocks x 256 threads; block = 2048 A-points (8/thread) x
// 256 B-points staged in LDS as pairs:
//   sP[jp] = {-2x0,-2x1,-2y0,-2y1}   sQ[jp] = {-2z0,-2z1, nb0, nb1}
// Pair cost = 3 fma + 1/2 min3 = 3.5 VALU ops. Per (8A x 2B) group:
// 2 ds_read_b128 feed 1024 lane-pairs -> LDS stays under VALU.
// Cross-chunk combine via atomicMin on monotone uint keys (exact min ->
// order-independent -> deterministic). Min table init'd to 0xFF per call.

#define N2K 2048
#define N8K 8192
#define THREADS 256
#define BBLK 256
// min-table uint layout in ws:
//   [0,      65536)  d1: b*8192 + a          (A=data, 8 chunks)
//   [65536,  81920)  d2: b*2048 + a          (A=rec, 32 chunks)
//   [81920, 147456)  p1: b*8192 + p*2048 + a (A=data seg, 8 chunks)
//   [147456,212992)  p2: b*8192 + p*2048 + a (A=recp seg, 8 chunks)
// float partials at [212992, 213200)
#define D1_BASE 0
#define D2_BASE 65536
#define P1_BASE 81920
#define P2_BASE 147456
#define NMINS 212992
#define PART_BASE 212992

__global__ __launch_bounds__(THREADS) void chamfer_kernel(
    const float* __restrict__ data,
    const float* __restrict__ rec,
    const float* __restrict__ recp,
    unsigned int* __restrict__ mins)
{
    __shared__ float4 sP[BBLK / 2];   // {-2x0,-2x1,-2y0,-2y1}
    __shared__ float4 sQ[BBLK / 2];   // {-2z0,-2z1, nb0, nb1}

    const int bid = blockIdx.x;       // 1024 blocks, 256 per role
    const int role = bid >> 8;        // 0=d1 1=d2 2=p1 3=p2
    const int r = bid & 255;
    const int b = r >> 5;             // batch
    const int rr = r & 31;

    const float* Ab; int As; int aOff;
    const float* Bb; int Bs; int bOff;
    int mbase;

    if (role == 0) {                  // d1: A=data[b], B=rec[b]
        int At = rr >> 3, Bc = rr & 7;           // 4 A-tiles x 8 B-chunks
        Ab = data + b * 3 * N8K; As = N8K; aOff = At * 2048;
        Bb = rec  + b * 3 * N2K; Bs = N2K; bOff = Bc * BBLK;
        mbase = D1_BASE + b * N8K + aOff;
    } else if (role == 1) {           // d2: A=rec[b], B=data[b]
        int Bc = rr;                             // 1 A-tile x 32 B-chunks
        Ab = rec  + b * 3 * N2K; As = N2K; aOff = 0;
        Bb = data + b * 3 * N8K; Bs = N8K; bOff = Bc * BBLK;
        mbase = D2_BASE + b * N2K;
    } else if (role == 2) {           // p1: A=data seg(b,p), B=recp seg(b,p)
        int p = rr >> 3, Bc = rr & 7;            // 4 parts x 8 B-chunks
        Ab = data + b * 3 * N8K; As = N8K; aOff = p * N2K;
        Bb = recp + b * 3 * N8K; Bs = N8K; bOff = p * N2K + Bc * BBLK;
        mbase = P1_BASE + b * N8K + p * N2K;
    } else {                          // p2: A=recp seg(b,p), B=data seg(b,p)
        int p = rr >> 3, Bc = rr & 7;
        Ab = recp + b * 3 * N8K; As = N8K; aOff = p * N2K;
        Bb = data + b * 3 * N8K; Bs = N8K; bOff = p * N2K + Bc * BBLK;
        mbase = P2_BASE + b * N8K + p * N2K;
    }

    const int tid = threadIdx.x;

    // Stage 256 B points as 128 pairs (threads 0-127)
    if (tid < BBLK / 2) {
        int j0 = bOff + 2 * tid, j1 = j0 + 1;
        float x0 = Bb[j0], y0 = Bb[Bs + j0], z0 = Bb[2 * Bs + j0];
        float x1 = Bb[j1], y1 = Bb[Bs + j1], z1 = Bb[2 * Bs + j1];
        sP[tid] = make_float4(-2.f * x0, -2.f * x1, -2.f * y0, -2.f * y1);
        sQ[tid] = make_float4(-2.f * z0, -2.f * z1,
                              x0 * x0 + y0 * y0 + z0 * z0,
                              x1 * x1 + y1 * y1 + z1 * z1);
    }

    // Eight A points per thread (coalesced: tid + i*256)
    float ax[8], ay[8], az[8], na[8], m[8];
    #pragma unroll
    for (int i = 0; i < 8; ++i) {
        int idx = aOff + i * THREADS + tid;
        ax[i] = Ab[idx]; ay[i] = Ab[As + idx]; az[i] = Ab[2 * As + idx];
        na[i] = ax[i] * ax[i] + ay[i] * ay[i] + az[i] * az[i];
        m[i] = 3.4e38f;
    }

    __syncthreads();

    // 128 pair-groups; per group: 2 ds_read_b128 + 8 x (6 fma + 1 min3)
    #pragma unroll 2
    for (int jp = 0; jp < BBLK / 2; ++jp) {   // wave-uniform -> LDS broadcast
        float4 P = sP[jp], Q = sQ[jp];
        #pragma unroll
        for (int i = 0; i < 8; ++i) {
            float dA = fmaf(ax[i], P.x, fmaf(ay[i], P.z, fmaf(az[i], Q.x, Q.z)));
            float dB = fmaf(ax[i], P.y, fmaf(ay[i], P.w, fmaf(az[i], Q.y, Q.w)));
            m[i] = fminf(fminf(dA, dB), m[i]);   // -> v_min3_f32
        }
    }

    // Fold per-A mins into global table: monotone key + atomicMin (exact)
    #pragma unroll
    for (int i = 0; i < 8; ++i) {
        float v = na[i] + m[i];
        unsigned int bu = __float_as_uint(v);
        unsigned int key = (bu & 0x80000000u) ? ~bu : (bu | 0x80000000u);
        atomicMin(&mins[mbase + i * THREADS + tid], key);
    }
}

__global__ __launch_bounds__(THREADS) void finalize1_kernel(
    const unsigned int* __restrict__ mins, float* __restrict__ part)
{
    __shared__ float sred[4];
    const int blk = blockIdx.x;        // 208 blocks x 1024 entries
    const int tid = threadIdx.x;

    float s = 0.f;
    #pragma unroll
    for (int i = 0; i < 4; ++i) {
        int idx = blk * 1024 + i * THREADS + tid;
        unsigned int k = mins[idx];
        unsigned int bu = (k & 0x80000000u) ? (k & 0x7FFFFFFFu) : ~k;
        float v = __uint_as_float(bu);
        float w = (idx < 65536) ? (1.f / 65536.f) : (1.f / 16384.f);
        s += v * w;
    }

    #pragma unroll
    for (int o = 32; o > 0; o >>= 1) s += __shfl_down(s, o, 64);
    const int lane = tid & 63, wid = tid >> 6;
    if (lane == 0) sred[wid] = s;
    __syncthreads();
    if (tid == 0)
        part[blk] = (sred[0] + sred[1]) + (sred[2] + sred[3]);
}

__global__ __launch_bounds__(THREADS) void finalize2_kernel(
    const float* __restrict__ part, float* __restrict__ out)
{
    __shared__ float sred[4];
    const int tid = threadIdx.x;
    float s = (tid < 208) ? part[tid] : 0.f;
    #pragma unroll
    for (int o = 32; o > 0; o >>= 1) s += __shfl_down(s, o, 64);
    const int lane = tid & 63, wid = tid >> 6;
    if (lane == 0) sred[wid] = s;
    __syncthreads();
    if (tid == 0)
        out[0] = ((sred[0] + sred[1]) + (sred[2] + sred[3])) * 0.2f;  // /5
}

extern "C" void kernel_launch(void* const* d_in, const int* in_sizes, int n_in,
                              void* d_out, int out_size, void* d_ws, size_t ws_size,
                              hipStream_t stream) {
    const float* data = (const float*)d_in[0];
    const float* rec  = (const float*)d_in[1];
    const float* recp = (const float*)d_in[2];
    float* out = (float*)d_out;
    unsigned int* mins = (unsigned int*)d_ws;
    float* part = (float*)d_ws + PART_BASE;

    // init min table to key-max (0xFFFFFFFF > any real key)
    hipMemsetAsync(d_ws, 0xFF, NMINS * sizeof(unsigned int), stream);
    chamfer_kernel<<<1024, THREADS, 0, stream>>>(data, rec, recp, mins);
    finalize1_kernel<<<208, THREADS, 0, stream>>>(mins, part);
    finalize2_kernel<<<1, THREADS, 0, stream>>>(part, out);
}

// Round 7
// 50.087 us; speedup vs baseline: 1.0608x; 1.0608x over previous
//
#include <hip/hip_runtime.h>

// Chamfer loss: global (data vs rec) + per-part (data seg vs recp seg).
// R4 geometry (proven fastest): 1024 uniform blocks x 256 threads; block =
// 1024 A-points (4/thread) x 512 B-points. B staged in LDS as PAIRS:
//   sP[jp] = {-2x0,-2x1,-2y0,-2y1}   sQ[jp] = {-2z0,-2z1, nb0, nb1}
// Pair cost = 3 fma + 1/2 min3 = 3.5 VALU ops, with v_min3_f32 FORCED via
// inline asm (fminf(fminf(..)..) fusion is not guaranteed).
// All roles B-chunked; per-A chunk-mins to ws (chunk-major, coalesced);
// finalize1 min-over-chunks + weighted sums; finalize2 folds partials.
// Fixed reduction order -> deterministic.

#define N2K 2048
#define N8K 8192
#define THREADS 256
#define ABLK 1024
#define BBLK 512
// ws float layout (same as round 4 — known-safe size):
//   [0,       262144) d1 mins: c*65536 + b*8192 + a   (C=4)
//   [262144,  524288) d2 mins: c*16384 + b*2048 + a   (C=16)
//   [524288,  786432) p1 mins: c*65536 + b*8192 + a   (C=4)
//   [786432, 1048576) p2 mins: c*65536 + b*8192 + a   (C=4)
//   [1048576, 1048832) 256 finalize1 partials
#define D1_BASE 0
#define D2_BASE 262144
#define P1_BASE 524288
#define P2_BASE 786432
#define PART_BASE 1048576

__device__ __forceinline__ float min3(float a, float b, float c) {
    float d;
    asm("v_min3_f32 %0, %1, %2, %3" : "=v"(d) : "v"(a), "v"(b), "v"(c));
    return d;
}

__global__ __launch_bounds__(THREADS) void chamfer_kernel(
    const float* __restrict__ data,
    const float* __restrict__ rec,
    const float* __restrict__ recp,
    float* __restrict__ ws)
{
    __shared__ float4 sP[BBLK / 2];   // {-2x0,-2x1,-2y0,-2y1}
    __shared__ float4 sQ[BBLK / 2];   // {-2z0,-2z1, nb0, nb1}

    const int bid = blockIdx.x;       // 1024 blocks, 256 per role
    const int role = bid >> 8;        // 0=d1 1=d2 2=p1 3=p2
    const int t = bid & 255;
    const int b = t >> 5;             // batch
    const int r = t & 31;

    const float* Ab; int As; int aOff;
    const float* Bb; int Bs; int bOff;
    int wbase;

    if (role == 0) {                  // d1: A=data[b], B=rec[b]
        int At = r >> 2, Bc = r & 3;          // 8 A-tiles x 4 B-chunks
        Ab = data + b * 3 * N8K; As = N8K; aOff = At * ABLK;
        Bb = rec  + b * 3 * N2K; Bs = N2K; bOff = Bc * BBLK;
        wbase = D1_BASE + Bc * 65536 + b * N8K + aOff;
    } else if (role == 1) {           // d2: A=rec[b], B=data[b]
        int At = r >> 4, Bc = r & 15;         // 2 A-tiles x 16 B-chunks
        Ab = rec  + b * 3 * N2K; As = N2K; aOff = At * ABLK;
        Bb = data + b * 3 * N8K; Bs = N8K; bOff = Bc * BBLK;
        wbase = D2_BASE + Bc * 16384 + b * N2K + aOff;
    } else if (role == 2) {           // p1: A=data seg(b,p), B=recp seg(b,p)
        int p = r >> 3, r2 = r & 7;
        int At = r2 >> 2, Bc = r2 & 3;        // 2 A-tiles x 4 B-chunks
        Ab = data + b * 3 * N8K; As = N8K; aOff = p * N2K + At * ABLK;
        Bb = recp + b * 3 * N8K; Bs = N8K; bOff = p * N2K + Bc * BBLK;
        wbase = P1_BASE + Bc * 65536 + b * N8K + aOff;
    } else {                          // p2: A=recp seg(b,p), B=data seg(b,p)
        int p = r >> 3, r2 = r & 7;
        int At = r2 >> 2, Bc = r2 & 3;
        Ab = recp + b * 3 * N8K; As = N8K; aOff = p * N2K + At * ABLK;
        Bb = data + b * 3 * N8K; Bs = N8K; bOff = p * N2K + Bc * BBLK;
        wbase = P2_BASE + Bc * 65536 + b * N8K + aOff;
    }

    const int tid = threadIdx.x;

    // Stage 512 B points as 256 pairs (1 pair per thread)
    {
        int j0 = bOff + 2 * tid, j1 = j0 + 1;
        float x0 = Bb[j0], y0 = Bb[Bs + j0], z0 = Bb[2 * Bs + j0];
        float x1 = Bb[j1], y1 = Bb[Bs + j1], z1 = Bb[2 * Bs + j1];
        sP[tid] = make_float4(-2.f * x0, -2.f * x1, -2.f * y0, -2.f * y1);
        sQ[tid] = make_float4(-2.f * z0, -2.f * z1,
                              x0 * x0 + y0 * y0 + z0 * z0,
                              x1 * x1 + y1 * y1 + z1 * z1);
    }

    // Four A points per thread (coalesced: tid + i*256)
    float ax[4], ay[4], az[4], na[4], m[4];
    #pragma unroll
    for (int i = 0; i < 4; ++i) {
        int idx = aOff + i * THREADS + tid;
        ax[i] = Ab[idx]; ay[i] = Ab[As + idx]; az[i] = Ab[2 * As + idx];
        na[i] = ax[i] * ax[i] + ay[i] * ay[i] + az[i] * az[i];
        m[i] = 3.4e38f;
    }

    __syncthreads();

    // 256 pair-groups; per group: 2 ds_read_b128 + 4 x (6 fma + 1 min3)
    #pragma unroll 4
    for (int jp = 0; jp < BBLK / 2; ++jp) {   // wave-uniform -> LDS broadcast
        float4 P = sP[jp], Q = sQ[jp];
        #pragma unroll
        for (int i = 0; i < 4; ++i) {
            float dA = fmaf(ax[i], P.x, fmaf(ay[i], P.z, fmaf(az[i], Q.x, Q.z)));
            float dB = fmaf(ax[i], P.y, fmaf(ay[i], P.w, fmaf(az[i], Q.y, Q.w)));
            m[i] = min3(m[i], dA, dB);
        }
    }

    #pragma unroll
    for (int i = 0; i < 4; ++i)
        ws[wbase + i * THREADS + tid] = na[i] + m[i];   // coalesced
}

__global__ __launch_bounds__(THREADS) void finalize1_kernel(
    const float* __restrict__ ws, float* __restrict__ part)
{
    __shared__ float sred[4];
    const int blk = blockIdx.x;        // 256 blocks: 64 per role
    const int role = blk >> 6;
    const int k = blk & 63;
    const int tid = threadIdx.x;

    float s = 0.f;
    float w;
    if (role == 1) {                   // d2: 256 A per block, C=16
        int a = k * 256 + tid;
        float v = 3.4e38f;
        #pragma unroll
        for (int c = 0; c < 16; ++c)
            v = fminf(v, ws[D2_BASE + c * 16384 + a]);
        s = v; w = 1.f / 16384.f;
    } else {                           // d1/p1/p2: 1024 A per block, C=4
        int base = (role == 0) ? D1_BASE : (role == 2) ? P1_BASE : P2_BASE;
        w = (role == 0) ? (1.f / 65536.f) : (1.f / 16384.f);
        #pragma unroll
        for (int i = 0; i < 4; ++i) {
            int a = k * 1024 + i * 256 + tid;
            float v = fminf(fminf(ws[base + a],          ws[base + 65536 + a]),
                            fminf(ws[base + 131072 + a], ws[base + 196608 + a]));
            s += v;
        }
    }
    s *= w;

    #pragma unroll
    for (int o = 32; o > 0; o >>= 1) s += __shfl_down(s, o, 64);
    const int lane = tid & 63, wid = tid >> 6;
    if (lane == 0) sred[wid] = s;
    __syncthreads();
    if (tid == 0)
        part[blk] = (sred[0] + sred[1]) + (sred[2] + sred[3]);
}

__global__ __launch_bounds__(THREADS) void finalize2_kernel(
    const float* __restrict__ part, float* __restrict__ out)
{
    __shared__ float sred[4];
    const int tid = threadIdx.x;
    float s = part[tid];
    #pragma unroll
    for (int o = 32; o > 0; o >>= 1) s += __shfl_down(s, o, 64);
    const int lane = tid & 63, wid = tid >> 6;
    if (lane == 0) sred[wid] = s;
    __syncthreads();
    if (tid == 0)
        out[0] = ((sred[0] + sred[1]) + (sred[2] + sred[3])) * 0.2f;  // /5
}

extern "C" void kernel_launch(void* const* d_in, const int* in_sizes, int n_in,
                              void* d_out, int out_size, void* d_ws, size_t ws_size,
                              hipStream_t stream) {
    const float* data = (const float*)d_in[0];
    const float* rec  = (const float*)d_in[1];
    const float* recp = (const float*)d_in[2];
    float* out = (float*)d_out;
    float* ws  = (float*)d_ws;

    chamfer_kernel<<<1024, THREADS, 0, stream>>>(data, rec, recp, ws);
    finalize1_kernel<<<256, THREADS, 0, stream>>>(ws, ws + PART_BASE);
    finalize2_kernel<<<1, THREADS, 0, stream>>>(ws + PART_BASE, out);
}

// Round 8
// 48.161 us; speedup vs baseline: 1.1032x; 1.0400x over previous
//
#include <hip/hip_runtime.h>

// Chamfer loss: global (data vs rec) + per-part (data seg vs recp seg).
// R7 geometry (1024 uniform blocks x 256 threads; block = 1024 A (4/thread)
// x 512 B) with PACKED inner math:
//   B staged in LDS as pairs: sP[jp]={-2x0,-2x1,-2y0,-2y1}
//                             sQ[jp]={-2z0,-2z1, nb0, nb1}
//   per (1A x 2B): 3 v_pk_fma_f32 + 1 v_min3_f32  = 2 VALU inst/pair.
// A coords pre-duplicated {a,a} so pk_fma broadcasts for free.
// All roles B-chunked; per-A chunk-mins to ws (chunk-major, coalesced);
// finalize1 min-over-chunks + weighted sums; finalize2 folds partials.
// Fixed reduction order -> deterministic.

#define N2K 2048
#define N8K 8192
#define THREADS 256
#define ABLK 1024
#define BBLK 512
// ws float layout (same as R4/R7 — known-safe size):
//   [0,       262144) d1 mins: c*65536 + b*8192 + a   (C=4)
//   [262144,  524288) d2 mins: c*16384 + b*2048 + a   (C=16)
//   [524288,  786432) p1 mins: c*65536 + b*8192 + a   (C=4)
//   [786432, 1048576) p2 mins: c*65536 + b*8192 + a   (C=4)
//   [1048576, 1048832) 256 finalize1 partials
#define D1_BASE 0
#define D2_BASE 262144
#define P1_BASE 524288
#define P2_BASE 786432
#define PART_BASE 1048576

typedef float f2 __attribute__((ext_vector_type(2)));

__device__ __forceinline__ float min3(float a, float b, float c) {
    float d;
    asm("v_min3_f32 %0, %1, %2, %3" : "=v"(d) : "v"(a), "v"(b), "v"(c));
    return d;
}

__global__ __launch_bounds__(THREADS) void chamfer_kernel(
    const float* __restrict__ data,
    const float* __restrict__ rec,
    const float* __restrict__ recp,
    float* __restrict__ ws)
{
    __shared__ float4 sP[BBLK / 2];   // {-2x0,-2x1,-2y0,-2y1}
    __shared__ float4 sQ[BBLK / 2];   // {-2z0,-2z1, nb0, nb1}

    const int bid = blockIdx.x;       // 1024 blocks, 256 per role
    const int role = bid >> 8;        // 0=d1 1=d2 2=p1 3=p2
    const int t = bid & 255;
    const int b = t >> 5;             // batch
    const int r = t & 31;

    const float* Ab; int As; int aOff;
    const float* Bb; int Bs; int bOff;
    int wbase;

    if (role == 0) {                  // d1: A=data[b], B=rec[b]
        int At = r >> 2, Bc = r & 3;          // 8 A-tiles x 4 B-chunks
        Ab = data + b * 3 * N8K; As = N8K; aOff = At * ABLK;
        Bb = rec  + b * 3 * N2K; Bs = N2K; bOff = Bc * BBLK;
        wbase = D1_BASE + Bc * 65536 + b * N8K + aOff;
    } else if (role == 1) {           // d2: A=rec[b], B=data[b]
        int At = r >> 4, Bc = r & 15;         // 2 A-tiles x 16 B-chunks
        Ab = rec  + b * 3 * N2K; As = N2K; aOff = At * ABLK;
        Bb = data + b * 3 * N8K; Bs = N8K; bOff = Bc * BBLK;
        wbase = D2_BASE + Bc * 16384 + b * N2K + aOff;
    } else if (role == 2) {           // p1: A=data seg(b,p), B=recp seg(b,p)
        int p = r >> 3, r2 = r & 7;
        int At = r2 >> 2, Bc = r2 & 3;        // 2 A-tiles x 4 B-chunks
        Ab = data + b * 3 * N8K; As = N8K; aOff = p * N2K + At * ABLK;
        Bb = recp + b * 3 * N8K; Bs = N8K; bOff = p * N2K + Bc * BBLK;
        wbase = P1_BASE + Bc * 65536 + b * N8K + aOff;
    } else {                          // p2: A=recp seg(b,p), B=data seg(b,p)
        int p = r >> 3, r2 = r & 7;
        int At = r2 >> 2, Bc = r2 & 3;
        Ab = recp + b * 3 * N8K; As = N8K; aOff = p * N2K + At * ABLK;
        Bb = data + b * 3 * N8K; Bs = N8K; bOff = p * N2K + Bc * BBLK;
        wbase = P2_BASE + Bc * 65536 + b * N8K + aOff;
    }

    const int tid = threadIdx.x;

    // Stage 512 B points as 256 pairs (1 pair per thread)
    {
        int j0 = bOff + 2 * tid, j1 = j0 + 1;
        float x0 = Bb[j0], y0 = Bb[Bs + j0], z0 = Bb[2 * Bs + j0];
        float x1 = Bb[j1], y1 = Bb[Bs + j1], z1 = Bb[2 * Bs + j1];
        sP[tid] = make_float4(-2.f * x0, -2.f * x1, -2.f * y0, -2.f * y1);
        sQ[tid] = make_float4(-2.f * z0, -2.f * z1,
                              x0 * x0 + y0 * y0 + z0 * z0,
                              x1 * x1 + y1 * y1 + z1 * z1);
    }

    // Four A points per thread (coalesced: tid + i*256), duplicated {a,a}
    f2 ax2[4], ay2[4], az2[4];
    float na[4], m[4];
    #pragma unroll
    for (int i = 0; i < 4; ++i) {
        int idx = aOff + i * THREADS + tid;
        float x = Ab[idx], y = Ab[As + idx], z = Ab[2 * As + idx];
        ax2[i] = (f2){x, x}; ay2[i] = (f2){y, y}; az2[i] = (f2){z, z};
        na[i] = x * x + y * y + z * z;
        m[i] = 3.4e38f;
    }

    __syncthreads();

    // 256 pair-groups; per group: 2 ds_read_b128 + 4 x (3 pk_fma + 1 min3)
    #pragma unroll 4
    for (int jp = 0; jp < BBLK / 2; ++jp) {   // wave-uniform -> LDS broadcast
        float4 P = sP[jp], Q = sQ[jp];
        f2 px = (f2){P.x, P.y}, py = (f2){P.z, P.w};
        f2 pz = (f2){Q.x, Q.y}, pw = (f2){Q.z, Q.w};
        #pragma unroll
        for (int i = 0; i < 4; ++i) {
            f2 d = __builtin_elementwise_fma(az2[i], pz, pw);
            d = __builtin_elementwise_fma(ay2[i], py, d);
            d = __builtin_elementwise_fma(ax2[i], px, d);
            m[i] = min3(m[i], d.x, d.y);
        }
    }

    #pragma unroll
    for (int i = 0; i < 4; ++i)
        ws[wbase + i * THREADS + tid] = na[i] + m[i];   // coalesced
}

__global__ __launch_bounds__(THREADS) void finalize1_kernel(
    const float* __restrict__ ws, float* __restrict__ part)
{
    __shared__ float sred[4];
    const int blk = blockIdx.x;        // 256 blocks: 64 per role
    const int role = blk >> 6;
    const int k = blk & 63;
    const int tid = threadIdx.x;

    float s = 0.f;
    float w;
    if (role == 1) {                   // d2: 256 A per block, C=16
        int a = k * 256 + tid;
        float v = 3.4e38f;
        #pragma unroll
        for (int c = 0; c < 16; ++c)
            v = fminf(v, ws[D2_BASE + c * 16384 + a]);
        s = v; w = 1.f / 16384.f;
    } else {                           // d1/p1/p2: 1024 A per block, C=4
        int base = (role == 0) ? D1_BASE : (role == 2) ? P1_BASE : P2_BASE;
        w = (role == 0) ? (1.f / 65536.f) : (1.f / 16384.f);
        #pragma unroll
        for (int i = 0; i < 4; ++i) {
            int a = k * 1024 + i * 256 + tid;
            float v = fminf(fminf(ws[base + a],          ws[base + 65536 + a]),
                            fminf(ws[base + 131072 + a], ws[base + 196608 + a]));
            s += v;
        }
    }
    s *= w;

    #pragma unroll
    for (int o = 32; o > 0; o >>= 1) s += __shfl_down(s, o, 64);
    const int lane = tid & 63, wid = tid >> 6;
    if (lane == 0) sred[wid] = s;
    __syncthreads();
    if (tid == 0)
        part[blk] = (sred[0] + sred[1]) + (sred[2] + sred[3]);
}

__global__ __launch_bounds__(THREADS) void finalize2_kernel(
    const float* __restrict__ part, float* __restrict__ out)
{
    __shared__ float sred[4];
    const int tid = threadIdx.x;
    float s = part[tid];
    #pragma unroll
    for (int o = 32; o > 0; o >>= 1) s += __shfl_down(s, o, 64);
    const int lane = tid & 63, wid = tid >> 6;
    if (lane == 0) sred[wid] = s;
    __syncthreads();
    if (tid == 0)
        out[0] = ((sred[0] + sred[1]) + (sred[2] + sred[3])) * 0.2f;  // /5
}

extern "C" void kernel_launch(void* const* d_in, const int* in_sizes, int n_in,
                              void* d_out, int out_size, void* d_ws, size_t ws_size,
                              hipStream_t stream) {
    const float* data = (const float*)d_in[0];
    const float* rec  = (const float*)d_in[1];
    const float* recp = (const float*)d_in[2];
    float* out = (float*)d_out;
    float* ws  = (float*)d_ws;

    chamfer_kernel<<<1024, THREADS, 0, stream>>>(data, rec, recp, ws);
    finalize1_kernel<<<256, THREADS, 0, stream>>>(ws, ws + PART_BASE);
    finalize2_kernel<<<1, THREADS, 0, stream>>>(ws + PART_BASE, out);
}